// Round 3
// baseline (756.966 us; speedup 1.0000x reference)
//
#include <hip/hip_runtime.h>
#include <math.h>

typedef unsigned short u16;
typedef __bf16 bf16;
typedef __attribute__((ext_vector_type(8))) __bf16 bf16x8;
typedef __attribute__((ext_vector_type(4))) __bf16 bf16x4;
typedef __attribute__((ext_vector_type(8))) short s16x8;
typedef __attribute__((ext_vector_type(4))) short s16x4;
typedef __attribute__((ext_vector_type(4))) float f32x4;

#define D_ 128

__device__ __forceinline__ float bf2f(u16 u) {
  union { unsigned int i; float f; } v; v.i = ((unsigned int)u) << 16; return v.f;
}
__device__ __forceinline__ u16 f2bf(float f) {
  union { float f; unsigned int i; } v; v.f = f;
  unsigned int r = v.i + 0x7fffu + ((v.i >> 16) & 1u);
  return (u16)(r >> 16);
}
__device__ __forceinline__ bf16 f2b(float f) {
  union { u16 u; bf16 b; } c; c.u = f2bf(f); return c.b;
}

// ---------------- Kernel 1: hn = rmsnorm(h); qkv = hn @ W_h ----------------
__global__ __launch_bounds__(384) void k_qkv(
    const float* __restrict__ hp, const float* __restrict__ Wh,
    const float* __restrict__ w1,
    float* __restrict__ qbuf, u16* __restrict__ kbuf, u16* __restrict__ vbuf) {
  const int row = blockIdx.x;   // b*512 + i
  const int t = threadIdx.x;    // 384 threads; one output col each
  __shared__ float hn[D_];
  __shared__ float red[6];
  float x = (t < D_) ? hp[row * D_ + t] : 0.f;
  float sq = x * x;
  #pragma unroll
  for (int off = 32; off; off >>= 1) sq += __shfl_down(sq, off, 64);
  if ((t & 63) == 0) red[t >> 6] = sq;
  __syncthreads();
  if (t < D_) {
    float ms = (red[0] + red[1]) * (1.f / 128.f);
    hn[t] = x * rsqrtf(ms + 1e-5f) * w1[t];
  }
  __syncthreads();
  float acc = 0.f;
  const f32x4* hn4 = (const f32x4*)hn;
  #pragma unroll 4
  for (int c4 = 0; c4 < 32; ++c4) {
    f32x4 hv = hn4[c4];
    const float* wp = Wh + c4 * 4 * 384 + t;
    acc += hv.x * wp[0];
    acc += hv.y * wp[384];
    acc += hv.z * wp[768];
    acc += hv.w * wp[1152];
  }
  if (t < 128)      qbuf[row * D_ + t] = acc;
  else if (t < 256) kbuf[row * D_ + (t - 128)] = f2bf(acc);
  else              vbuf[row * D_ + (t - 256)] = f2bf(acc);
}

// ---- Kernel 2: fused edge-projection (MFMA) + gated-softmax attention ----
// One block per (b,i). j-tiles of 64. e12[j,0:16] = e[b,i,j,:] @ W_e.
// s = q.k/4 + e1; p = exp(s); y = (sum p*e2*v) / (sum p).
//
// e MFMA A-fragments load DIRECTLY from global (no LDS e-tile). Every
// ebias/ps/pg producer-consumer pair is wave-local (wave wv owns e-rows
// wv*16..wv*16+15 of each tile), so the main loop has ZERO __syncthreads;
// wave_barrier() compiler fences keep phase ordering within each wave.
__global__ __launch_bounds__(256) void k_attn(
    const float* __restrict__ ep, const float* __restrict__ Wep,
    const float* __restrict__ qbuf, const u16* __restrict__ kbuf,
    const u16* __restrict__ vbuf, float* __restrict__ ybuf) {
  const int row = blockIdx.x;     // b*512 + i
  const int b = row >> 9;
  const int t = threadIdx.x;      // 256 threads = 4 waves
  const int lane = t & 63;
  const int wv = t >> 6;

  __shared__ float ebias[64][17];      // [j][o]: o<8 -> e1, o>=8 -> e2 (pad)
  __shared__ float ps[64][9];          // exp(s) (pad)
  __shared__ float pg[64][9];          // exp(s)*e2 (pad)
  __shared__ float rnum[4][128];       // per-wave partial numerators
  __shared__ float rden[4][8];         // per-wave partial denominators

  // Per-lane e fragment source: row wv*16+(lane&15), columns
  // kc*32 + (lane>>4)*8 .. +7  (exactly the MFMA A-fragment layout).
  const float* efrag = ep + (size_t)row * (512 * 128)
                     + (size_t)(wv * 16 + (lane & 15)) * 128 + (lane >> 4) * 8;

  // T14: issue tile-0 fragment loads first; they fly under the setup below.
  f32x4 bufA[8], bufB[8];
  #pragma unroll
  for (int kc = 0; kc < 4; ++kc) {
    const f32x4* p = (const f32x4*)(efrag + kc * 32);
    bufA[kc * 2]     = __builtin_nontemporal_load(p);
    bufA[kc * 2 + 1] = __builtin_nontemporal_load(p + 1);
  }

  // W_e B-fragments: B[k][n], n = lane&15, k = (lane>>4)*8 + jj, per K-chunk kc
  bf16x8 bfrag[4];
  #pragma unroll
  for (int kc = 0; kc < 4; ++kc) {
    #pragma unroll
    for (int jj = 0; jj < 8; ++jj)
      bfrag[kc][jj] = f2b(Wep[(kc * 32 + (lane >> 4) * 8 + jj) * 16 + (lane & 15)]);
  }

  // phase-C head for this thread; fold 1/sqrt(16) into q
  const int hC = t & 7;
  float qreg[16];
  {
    const f32x4* q4 = (const f32x4*)(qbuf + row * D_ + hC * 16);
    #pragma unroll
    for (int r = 0; r < 4; ++r) {
      f32x4 qv = q4[r] * 0.25f;
      *(f32x4*)(qreg + r * 4) = qv;
    }
  }

  // phase-D slot: j-group g (4 rows/tile), d-block dblk (8 contiguous d's)
  const int g = t >> 4;           // 0..15 (wave-local rows: g*4 in wv's quarter)
  const int dblk = t & 15;        // d = dblk*8 .. dblk*8+7
  const int hD = dblk >> 1;       // head of this d-block
  float num[8] = {0.f, 0.f, 0.f, 0.f, 0.f, 0.f, 0.f, 0.f};
  float den = 0.f;

#define ATTN_TILE(JT, CUR, NXT, PREF)                                          \
  {                                                                            \
    const int j0 = (JT) * 64;                                                  \
    if (PREF) {                                                                \
      const float* nsrc = efrag + (size_t)((JT) + 1) * (64 * 128);             \
      _Pragma("unroll")                                                        \
      for (int kc = 0; kc < 4; ++kc) {                                         \
        const f32x4* p = (const f32x4*)(nsrc + kc * 32);                       \
        NXT[kc * 2]     = __builtin_nontemporal_load(p);                       \
        NXT[kc * 2 + 1] = __builtin_nontemporal_load(p + 1);                   \
      }                                                                        \
    }                                                                          \
    /* Phase B: convert fragments + MFMA projection (rows wv*16..+15) */       \
    f32x4 cacc = {0.f, 0.f, 0.f, 0.f};                                         \
    _Pragma("unroll")                                                          \
    for (int kc = 0; kc < 4; ++kc) {                                           \
      f32x4 lo = CUR[kc * 2], hi = CUR[kc * 2 + 1];                            \
      bf16x8 af;                                                               \
      af[0] = (bf16)lo.x; af[1] = (bf16)lo.y;                                  \
      af[2] = (bf16)lo.z; af[3] = (bf16)lo.w;                                  \
      af[4] = (bf16)hi.x; af[5] = (bf16)hi.y;                                  \
      af[6] = (bf16)hi.z; af[7] = (bf16)hi.w;                                  \
      cacc = __builtin_amdgcn_mfma_f32_16x16x32_bf16(af, bfrag[kc], cacc,      \
                                                     0, 0, 0);                 \
    }                                                                          \
    _Pragma("unroll")                                                          \
    for (int r = 0; r < 4; ++r)                                                \
      ebias[wv * 16 + (lane >> 4) * 4 + r][lane & 15] = cacc[r];               \
    __builtin_amdgcn_wave_barrier();                                           \
    /* Phase C: scores + exp + gate; thread handles (2 j-rows, head hC) */     \
    _Pragma("unroll")                                                          \
    for (int jj = 0; jj < 2; ++jj) {                                           \
      int jl = ((t >> 3) << 1) + jj;                                           \
      const u16* kr = kbuf + ((size_t)(b * 512 + j0 + jl)) * 128 + hC * 16;    \
      s16x8 k0 = *(const s16x8*)(kr);                                          \
      s16x8 k1 = *(const s16x8*)(kr + 8);                                      \
      float s = ebias[jl][hC];                                                 \
      _Pragma("unroll")                                                        \
      for (int d = 0; d < 8; ++d) s += qreg[d] * bf2f((u16)k0[d]);             \
      _Pragma("unroll")                                                        \
      for (int d = 0; d < 8; ++d) s += qreg[8 + d] * bf2f((u16)k1[d]);         \
      float p = __expf(s);   /* |s| <~ 2, safe without max-subtraction */      \
      ps[jl][hC] = p;                                                          \
      pg[jl][hC] = p * ebias[jl][8 + hC];                                      \
    }                                                                          \
    __builtin_amdgcn_wave_barrier();                                           \
    /* Phase D: vectorized numerator/denominator accumulation */               \
    {                                                                          \
      const u16* vr = vbuf + ((size_t)(b * 512 + j0 + g * 4)) * 128 + dblk * 8;\
      _Pragma("unroll")                                                        \
      for (int jj = 0; jj < 4; ++jj) {                                         \
        s16x8 vv = *(const s16x8*)(vr + (size_t)jj * 128);                     \
        int jl = g * 4 + jj;                                                   \
        float p = pg[jl][hD];                                                  \
        den += ps[jl][hD];                                                     \
        _Pragma("unroll")                                                      \
        for (int u = 0; u < 8; ++u)                                            \
          num[u] += p * bf2f((u16)vv[u]);                                      \
      }                                                                        \
    }                                                                          \
    __builtin_amdgcn_wave_barrier();                                           \
  }

  for (int jp = 0; jp < 4; ++jp) {
    ATTN_TILE(2 * jp,     bufA, bufB, 1);
    ATTN_TILE(2 * jp + 1, bufB, bufA, (jp < 3));
  }
#undef ATTN_TILE

  // Reduce over the 4 j-groups within each wave (g = wv*4 + (lane>>4))
  #pragma unroll
  for (int u = 0; u < 8; ++u) {
    num[u] += __shfl_xor(num[u], 16, 64);
    num[u] += __shfl_xor(num[u], 32, 64);
  }
  den += __shfl_xor(den, 16, 64);
  den += __shfl_xor(den, 32, 64);
  if (lane < 16) {
    #pragma unroll
    for (int u = 0; u < 8; ++u) rnum[wv][(lane & 15) * 8 + u] = num[u];
    if (!(lane & 1)) rden[wv][lane >> 1] = den;
  }
  __syncthreads();
  if (t < 128) {
    float n = rnum[0][t] + rnum[1][t] + rnum[2][t] + rnum[3][t];
    float dd = rden[0][t >> 4] + rden[1][t >> 4] + rden[2][t >> 4] + rden[3][t >> 4];
    ybuf[row * D_ + t] = n / dd;
  }
}

// -------- Kernel 3: z = rmsnorm(y+h); out = gelu(z@Wfc)@Wproj + y ---------
// 4 rows per block to amortize fp32 weight reads through L2.
__global__ __launch_bounds__(512) void k_ffn(
    const float* __restrict__ hp, const float* __restrict__ w2,
    const float* __restrict__ Wfc, const float* __restrict__ Wpr,
    const float* __restrict__ ybuf, float* __restrict__ outp) {
  const int r0 = blockIdx.x * 4;   // rows r0..r0+3
  const int t = threadIdx.x;       // 512 threads
  const int r = t >> 7, c = t & 127;
  __shared__ float z[4][128];
  __shared__ float t1[4][512];
  __shared__ float red[8];
  __shared__ float m4[4][4][128];  // [part][row][col]
  __shared__ float yv_s[4][128];

  const int row = r0 + r;
  float yv = ybuf[row * 128 + c];
  float res = yv + hp[row * 128 + c];
  yv_s[r][c] = yv;
  float sq = res * res;
  #pragma unroll
  for (int off = 32; off; off >>= 1) sq += __shfl_down(sq, off, 64);
  if ((t & 63) == 0) red[t >> 6] = sq;
  __syncthreads();
  {
    float ms = (red[2 * r] + red[2 * r + 1]) * (1.f / 128.f);
    z[r][c] = res * rsqrtf(ms + 1e-5f) * w2[c];
  }
  __syncthreads();
  // FC1 + exact GELU: thread t computes hidden unit t for all 4 rows
  {
    float a0 = 0.f, a1 = 0.f, a2 = 0.f, a3 = 0.f;
    const f32x4* z0 = (const f32x4*)z[0];
    const f32x4* z1 = (const f32x4*)z[1];
    const f32x4* z2 = (const f32x4*)z[2];
    const f32x4* z3 = (const f32x4*)z[3];
    #pragma unroll 4
    for (int c4 = 0; c4 < 32; ++c4) {
      const float* wp = Wfc + c4 * 4 * 512 + t;
      float w0 = wp[0], w1_ = wp[512], w2_ = wp[1024], w3_ = wp[1536];
      f32x4 v;
      v = z0[c4]; a0 += v.x * w0 + v.y * w1_ + v.z * w2_ + v.w * w3_;
      v = z1[c4]; a1 += v.x * w0 + v.y * w1_ + v.z * w2_ + v.w * w3_;
      v = z2[c4]; a2 += v.x * w0 + v.y * w1_ + v.z * w2_ + v.w * w3_;
      v = z3[c4]; a3 += v.x * w0 + v.y * w1_ + v.z * w2_ + v.w * w3_;
    }
    t1[0][t] = 0.5f * a0 * (1.f + erff(a0 * 0.70710678118654752f));
    t1[1][t] = 0.5f * a1 * (1.f + erff(a1 * 0.70710678118654752f));
    t1[2][t] = 0.5f * a2 * (1.f + erff(a2 * 0.70710678118654752f));
    t1[3][t] = 0.5f * a3 * (1.f + erff(a3 * 0.70710678118654752f));
  }
  __syncthreads();
  // FC2: part = t>>7 covers FF chunk part*128..+127; col d = t&127; 4 rows
  {
    const int d = t & 127, part = t >> 7;
    float b0 = 0.f, b1 = 0.f, b2 = 0.f, b3 = 0.f;
    const f32x4* p0 = (const f32x4*)(t1[0] + part * 128);
    const f32x4* p1 = (const f32x4*)(t1[1] + part * 128);
    const f32x4* p2 = (const f32x4*)(t1[2] + part * 128);
    const f32x4* p3 = (const f32x4*)(t1[3] + part * 128);
    #pragma unroll 4
    for (int c4 = 0; c4 < 32; ++c4) {
      const float* wp = Wpr + (part * 128 + c4 * 4) * 128 + d;
      float w0 = wp[0], w1_ = wp[128], w2_ = wp[256], w3_ = wp[384];
      f32x4 v;
      v = p0[c4]; b0 += v.x * w0 + v.y * w1_ + v.z * w2_ + v.w * w3_;
      v = p1[c4]; b1 += v.x * w0 + v.y * w1_ + v.z * w2_ + v.w * w3_;
      v = p2[c4]; b2 += v.x * w0 + v.y * w1_ + v.z * w2_ + v.w * w3_;
      v = p3[c4]; b3 += v.x * w0 + v.y * w1_ + v.z * w2_ + v.w * w3_;
    }
    m4[part][0][d] = b0;
    m4[part][1][d] = b1;
    m4[part][2][d] = b2;
    m4[part][3][d] = b3;
  }
  __syncthreads();
  {
    float m = m4[0][r][c] + m4[1][r][c] + m4[2][r][c] + m4[3][r][c];
    outp[row * 128 + c] = m + yv_s[r][c];
  }
}

extern "C" void kernel_launch(void* const* d_in, const int* in_sizes, int n_in,
                              void* d_out, int out_size, void* d_ws, size_t ws_size,
                              hipStream_t stream) {
  const float* hp  = (const float*)d_in[0];
  const float* ep  = (const float*)d_in[1];
  const float* Wh  = (const float*)d_in[2];
  const float* We  = (const float*)d_in[3];
  const float* w1  = (const float*)d_in[4];
  const float* w2  = (const float*)d_in[5];
  const float* Wfc = (const float*)d_in[6];
  const float* Wpr = (const float*)d_in[7];
  float* outp = (float*)d_out;

  float* qbuf = (float*)d_ws;                 // 2048*128 fp32 = 1 MB
  u16* kbuf = (u16*)(qbuf + 2048 * 128);      // 2048*128 bf16 = 0.5 MB
  u16* vbuf = kbuf + 2048 * 128;              // 0.5 MB
  float* ybuf = (float*)(vbuf + 2048 * 128);  // 1 MB

  k_qkv<<<2048, 384, 0, stream>>>(hp, Wh, w1, qbuf, kbuf, vbuf);
  k_attn<<<2048, 256, 0, stream>>>(ep, We, qbuf, kbuf, vbuf, ybuf);
  k_ffn<<<512, 512, 0, stream>>>(hp, w2, Wfc, Wpr, ybuf, outp);
}